// Round 9
// baseline (230.600 us; speedup 1.0000x reference)
//
#include <hip/hip_runtime.h>

// Depthwise xcorr: out[p][oy][ox] = sum_{ky,kx} x[p][oy+ky][ox+kx] * z[p][ky][kx]
// 32768 planes. x: 31x31, z: 7x7, out: 25x25, fp32.
//
// Round 9: fix round-8's LDS overflow. STAGE issues 39*256 = 9984 slot writes
// but the buffer was 9920 floats -> last chunk's 64 overhang slots corrupted
// xs[1][0..63] (absmax 28.9). Buffers now padded to 9984 floats each
// (xs[2][9984] = 79872 B, still 2 blocks/CU). Structure unchanged:
//  - persistent 512 blocks (2/CU), PPB=10, 250/256 active lanes
//  - per tile: z->regs, STAGE(next tile -> other buf), compute(cur), barrier
//    (prefetch drains at a barrier one full compute phase later)
//  - x in LDS stride-32, XOR swizzle (c ^ ((row&7)<<2)), staged via
//    pre-swizzled GLOBAL source; LDS dest linear (both-sides rule)
//  - __launch_bounds__(256,2): 256-VGPR budget, no scratch spill (R7 lesson)

#define PPB 10
#define WX 31
#define XPLANE 961
#define LROW 32                 // LDS row stride in dwords (swizzled)
#define LPLANE (31 * LROW)      // 992
#define ZPLANE 49
#define OPLANE 625
#define WO 25
#define BUF (PPB * LPLANE)               // 9920 used floats
#define XCHUNKS ((BUF + 255) / 256)      // 39
#define BUFPAD (XCHUNKS * 256)           // 9984 alloc floats (64-slot pad)
#define GRID 512

typedef __attribute__((address_space(1))) const void gaddr_t;
typedef __attribute__((address_space(3))) void laddr_t;

__global__ __launch_bounds__(256, 2) void dwxcorr_kernel(
    const float* __restrict__ z, const float* __restrict__ x,
    float* __restrict__ out, int nplanes, int ntiles) {
  __shared__ float xs[2][BUFPAD];  // 79872 B -> 2 blocks/CU

  const int tid = threadIdx.x;
  const int wbase = tid & ~63;  // wave-uniform LDS chunk base

  const int cpp = tid / 25;     // plane within tile (0..9 for tid<250)
  const int t25 = tid - cpp * 25;
  const int ty = t25 / 5;
  const int tx = t25 - ty * 5;
  const int tx5 = tx * 5;
  const bool act0 = (tid < PPB * 25);

  // issue 39 async global->LDS loads; source pre-swizzled so LDS holds
  // LDS[pp][row][q] = x[pp][row][ q ^ ((row&7)<<2) ]  (clamped dups in pads)
  auto STAGE = [&](int buf, int tile) {
    const int p0 = tile * PPB;
    const int pmax = min(PPB, nplanes - p0);
    const long xoff = (long)p0 * XPLANE;
#pragma unroll
    for (int c = 0; c < XCHUNKS; ++c) {
      int s = c * 256 + tid;      // linear LDS slot (< BUFPAD, in-bounds)
      int rl = s >> 5;            // row-linear index
      int q = s & 31;
      int pp = rl / 31;
      int row = rl - pp * 31;
      if (pp >= pmax) { pp = pmax - 1; row = 30; }  // overhang/tail clamp
      int ccol = q ^ ((row & 7) << 2);
      ccol = (ccol > 30) ? 30 : ccol;  // col 31 doesn't exist: dup col 30
      long gi = xoff + pp * XPLANE + row * WX + ccol;
      __builtin_amdgcn_global_load_lds((gaddr_t*)(x + gi),
                                       (laddr_t*)&xs[buf][c * 256 + wbase],
                                       4, 0, 0);
    }
  };

  const int bstart = blockIdx.x;
  if (bstart >= ntiles) return;

  STAGE(0, bstart);
  __syncthreads();  // prologue drain

  int cur = 0;
  for (int t = bstart; t < ntiles; t += GRID, cur ^= 1) {
    const int p0 = t * PPB;
    const int pmax = min(PPB, nplanes - p0);

    // z -> regs, issued BEFORE next stage (older in vmcnt order)
    const int zp = p0 + min(cpp, pmax - 1);
    const float* zb = z + (long)min(zp, nplanes - 1) * ZPLANE;
    float zr[ZPLANE];
#pragma unroll
    for (int j = 0; j < ZPLANE; ++j) zr[j] = zb[j];

    // prefetch next tile into the other buffer (in flight through compute)
    const int tn = t + GRID;
    if (tn < ntiles) STAGE(cur ^ 1, tn);

    if (act0 && cpp < pmax) {
      float acc[5][5];
#pragma unroll
      for (int r = 0; r < 5; ++r)
#pragma unroll
        for (int j2 = 0; j2 < 5; ++j2) acc[r][j2] = 0.0f;

      const float* pb = &xs[cur][cpp * LPLANE];
#pragma unroll
      for (int iy = 0; iy < 11; ++iy) {
        const int row = ty * 5 + iy;
        const int rb = row * LROW;
        const int f = (row & 7) << 2;
        float xr[11];
#pragma unroll
        for (int k = 0; k < 11; ++k) xr[k] = pb[rb + ((tx5 + k) ^ f)];
        const int ky_lo = (iy - 4 < 0) ? 0 : iy - 4;
        const int ky_hi = (iy < 6) ? iy : 6;
#pragma unroll
        for (int ky = 0; ky < 7; ++ky) {
          if (ky < ky_lo || ky > ky_hi) continue;  // folds at compile time
          const int orow = iy - ky;
#pragma unroll
          for (int kx = 0; kx < 7; ++kx) {
            const float zv = zr[ky * 7 + kx];
#pragma unroll
            for (int j2 = 0; j2 < 5; ++j2)
              acc[orow][j2] = fmaf(xr[kx + j2], zv, acc[orow][j2]);
          }
        }
      }

      float* ob = out + (long)(p0 + cpp) * OPLANE + (ty * 5) * WO + tx5;
#pragma unroll
      for (int r = 0; r < 5; ++r)
#pragma unroll
        for (int j2 = 0; j2 < 5; ++j2) ob[r * WO + j2] = acc[r][j2];
    }

    __syncthreads();  // drains prefetch (had full compute phase) + buffer swap
  }
}

extern "C" void kernel_launch(void* const* d_in, const int* in_sizes, int n_in,
                              void* d_out, int out_size, void* d_ws, size_t ws_size,
                              hipStream_t stream) {
  const float* z = (const float*)d_in[0];  // [B,C,7,7]
  const float* x = (const float*)d_in[1];  // [B,C,31,31]
  float* out = (float*)d_out;              // [B,C,25,25]

  const int nplanes = in_sizes[0] / ZPLANE;        // 32768
  const int ntiles = (nplanes + PPB - 1) / PPB;    // 3277

  hipLaunchKernelGGL(dwxcorr_kernel, dim3(GRID), dim3(256), 0, stream,
                     z, x, out, nplanes, ntiles);
}

// Round 10
// 53.508 us; speedup vs baseline: 4.3097x; 4.3097x over previous
//
#include <hip/hip_runtime.h>

// Depthwise xcorr: out[p][oy][ox] = sum_{ky,kx} x[p][oy+ky][ox+kx] * z[p][ky][kx]
// 32768 planes. x: 31x31, z: 7x7, out: 25x25, fp32.
//
// Round 10: consolidation of R3-R9 lessons.
//  - z in LDS (NOT global->regs): R7/R9 proved global-held zr[49] forces the
//    compiler to keep 49 live VGPRs -> scratch spill (+140MB HBM). From LDS
//    the compiler sinks each read to first use (R5: VGPR=68, no spill).
//  - Plane stride 1280 floats (row stride 41 == 9 mod 32): banks within a
//    plane = 5*(9ty+tx) mod 32 -> 25 distinct banks except one FREE 2-way.
//    1280 = 10 chunks of 128 -> all staging div/mod is compile-time; the 10
//    within-plane (row*31+col) source offsets are precomputed ONCE per thread
//    -> staging ~2 VALU/chunk (R6's conflict fix without its 400-op math tax).
//  - 128-thread blocks, PPB=5: 125/128 active lanes (97.7%, R5-level).
//  - LDS 26624 B -> 6 blocks/CU (12 waves) for stage/compute overlap across
//    blocks; one-shot blocks (persistent dbuf gave no win and spilled).

#define PPB 5
#define WX 31
#define XPLANE 961
#define RS 41                    // LDS row stride (9 mod 32)
#define LPLANE 1280              // 31*41=1271 used + 9 pad; 10 chunks of 128
#define NCH (PPB * 10)           // 50 x-chunks
#define ZPLANE 49
#define ZFLOATS (PPB * ZPLANE)   // 245
#define OPLANE 625
#define WO 25

typedef __attribute__((address_space(1))) const void gaddr_t;
typedef __attribute__((address_space(3))) void laddr_t;

__global__ __launch_bounds__(128, 2) void dwxcorr_kernel(
    const float* __restrict__ z, const float* __restrict__ x,
    float* __restrict__ out, int nplanes) {
  __shared__ float xs[PPB * LPLANE];  // 25600 B
  __shared__ float zs[256];           //  1024 B -> 26624 B total, 6 blocks/CU

  const int tid = threadIdx.x;
  const int wbase = tid & ~63;        // wave-uniform LDS chunk base
  const int p0 = blockIdx.x * PPB;
  const int pmax = min(PPB, nplanes - p0);
  const long XTOT = (long)nplanes * XPLANE;
  const long ZTOT = (long)nplanes * ZPLANE;
  const long xoff = (long)p0 * XPLANE;
  const long zoff = (long)p0 * ZPLANE;

  // ---- precompute the 10 within-plane packed-source offsets (one-time) ----
  // padded slot s = i*128 + tid  ->  row = s/41 (clamp 30), col = s%41
  // (clamp 30; pad slots duplicate col/row 30, never read)
  int offx[10];
#pragma unroll
  for (int i = 0; i < 10; ++i) {
    int s = i * 128 + tid;
    int r = s / RS;                // compile-time magic-mul
    int col = s - r * RS;
    r = (r > 30) ? 30 : r;
    col = (col > 30) ? 30 : col;
    offx[i] = r * WX + col;
  }

  // ---- stage x: 50 async loads; LDS linear, source pre-padded/swizzled ----
#pragma unroll
  for (int c = 0; c < NCH; ++c) {
    const int pp = c / 10;             // compile-time
    const int i = c - pp * 10;         // compile-time
    long gi = xoff + pp * XPLANE + offx[i];
    if (gi >= XTOT) gi = XTOT - 1;     // tail-block clamp (dup, never read)
    __builtin_amdgcn_global_load_lds((gaddr_t*)(x + gi),
                                     (laddr_t*)&xs[c * 128 + wbase], 4, 0, 0);
  }
  // ---- stage z: 2 chunks, linear ----
#pragma unroll
  for (int c = 0; c < 2; ++c) {
    long gi = zoff + c * 128 + tid;
    if (gi >= ZTOT) gi = ZTOT - 1;     // also covers slots 245..255 (dup)
    __builtin_amdgcn_global_load_lds((gaddr_t*)(z + gi),
                                     (laddr_t*)&zs[c * 128 + wbase], 4, 0, 0);
  }
  __syncthreads();  // single drain + barrier

  // ---- compute: thread -> (plane cpp, 5x5 tile (ty,tx)); 125/128 active ----
  const int cpp = tid / 25;
  if (tid >= PPB * 25 || cpp >= pmax) return;
  const int t25 = tid - cpp * 25;
  const int ty = t25 / 5;
  const int tx = t25 - ty * 5;
  const int tx5 = tx * 5;

  // z from LDS: broadcast reads, compiler sinks to first use (low pressure)
  float zr[ZPLANE];
#pragma unroll
  for (int j = 0; j < ZPLANE; ++j) zr[j] = zs[cpp * ZPLANE + j];

  float acc[5][5];
#pragma unroll
  for (int r = 0; r < 5; ++r)
#pragma unroll
    for (int j = 0; j < 5; ++j) acc[r][j] = 0.0f;

  const float* pb = &xs[cpp * LPLANE + (ty * 5) * RS + tx5];

  // Stream 11 patch rows; row iy feeds output rows orow = iy-ky in [0,4]
#pragma unroll
  for (int iy = 0; iy < 11; ++iy) {
    float xr[11];
#pragma unroll
    for (int k = 0; k < 11; ++k) xr[k] = pb[iy * RS + k];
    const int ky_lo = (iy - 4 < 0) ? 0 : iy - 4;
    const int ky_hi = (iy < 6) ? iy : 6;
#pragma unroll
    for (int ky = 0; ky < 7; ++ky) {
      if (ky < ky_lo || ky > ky_hi) continue;  // folds at compile time
      const int orow = iy - ky;
#pragma unroll
      for (int kx = 0; kx < 7; ++kx) {
        const float zv = zr[ky * 7 + kx];
#pragma unroll
        for (int j = 0; j < 5; ++j)
          acc[orow][j] = fmaf(xr[kx + j], zv, acc[orow][j]);
      }
    }
  }

  // ---- write the 5x5 tile ----
  float* ob = out + (long)(p0 + cpp) * OPLANE + (ty * 5) * WO + tx5;
#pragma unroll
  for (int r = 0; r < 5; ++r)
#pragma unroll
    for (int j = 0; j < 5; ++j) ob[r * WO + j] = acc[r][j];
}

extern "C" void kernel_launch(void* const* d_in, const int* in_sizes, int n_in,
                              void* d_out, int out_size, void* d_ws, size_t ws_size,
                              hipStream_t stream) {
  const float* z = (const float*)d_in[0];  // [B,C,7,7]
  const float* x = (const float*)d_in[1];  // [B,C,31,31]
  float* out = (float*)d_out;              // [B,C,25,25]

  const int nplanes = in_sizes[0] / ZPLANE;      // 32768
  const int blocks = (nplanes + PPB - 1) / PPB;  // 6554

  hipLaunchKernelGGL(dwxcorr_kernel, dim3(blocks), dim3(128), 0, stream,
                     z, x, out, nplanes);
}